// Round 1
// baseline (161.377 us; speedup 1.0000x reference)
//
#include <hip/hip_runtime.h>
#include <math.h>

#define N_   16
#define L_   512
#define C_   256      // D == F == 256
#define T_   4096
#define TL   16       // rows (l positions) per conv block
#define EPSL 1e-5f

// ---------------------------------------------------------------------------
// Kernel 1: conv1d(K=3, same) + bias + LayerNorm + ReLU   (in,out: [N,L,256])
// Block: 256 threads (thread = out channel), handles TL consecutive l of one n.
// ---------------------------------------------------------------------------
__global__ __launch_bounds__(256) void conv_ln_relu_kernel(
    const float* __restrict__ in, const float* __restrict__ w,
    const float* __restrict__ bias, const float* __restrict__ g,
    const float* __restrict__ beta, float* __restrict__ out)
{
    __shared__ float xt[TL + 2][C_];
    __shared__ float red[4][TL];

    const int c    = threadIdx.x;
    const int lane = c & 63, wid = c >> 6;
    const int tile = blockIdx.x % (L_ / TL);
    const int n    = blockIdx.x / (L_ / TL);
    const int l0   = tile * TL;

    // stage rows l0-1 .. l0+TL (zero padded)
    for (int r = 0; r < TL + 2; ++r) {
        int l = l0 - 1 + r;
        float v = 0.f;
        if (l >= 0 && l < L_) v = in[((size_t)n * L_ + l) * C_ + c];
        xt[r][c] = v;
    }
    __syncthreads();

    float acc[TL];
    #pragma unroll
    for (int i = 0; i < TL; ++i) acc[i] = 0.f;

    const float* wp = w + c;          // w[k][cin][c] = wp[(k*256+cin)*256]
    for (int cin = 0; cin < C_; ++cin) {
        float xv[TL + 2];
        #pragma unroll
        for (int r = 0; r < TL + 2; ++r) xv[r] = xt[r][cin];
        float w0 = wp[(size_t)cin * 256];
        float w1 = wp[(size_t)(256 + cin) * 256];
        float w2 = wp[(size_t)(512 + cin) * 256];
        #pragma unroll
        for (int i = 0; i < TL; ++i)
            acc[i] = fmaf(w0, xv[i], fmaf(w1, xv[i + 1], fmaf(w2, xv[i + 2], acc[i])));
    }

    const float bia = bias[c], gg = g[c], bb = beta[c];
    #pragma unroll
    for (int i = 0; i < TL; ++i) acc[i] += bia;

    // LayerNorm over channels (two-pass, matches jnp.mean/var)
    float mean[TL];
    #pragma unroll
    for (int i = 0; i < TL; ++i) {
        float s = acc[i];
        #pragma unroll
        for (int off = 32; off > 0; off >>= 1) s += __shfl_down(s, off);
        if (lane == 0) red[wid][i] = s;
    }
    __syncthreads();
    #pragma unroll
    for (int i = 0; i < TL; ++i)
        mean[i] = (red[0][i] + red[1][i] + red[2][i] + red[3][i]) * (1.f / 256.f);
    __syncthreads();
    #pragma unroll
    for (int i = 0; i < TL; ++i) {
        float d = acc[i] - mean[i];
        float s = d * d;
        #pragma unroll
        for (int off = 32; off > 0; off >>= 1) s += __shfl_down(s, off);
        if (lane == 0) red[wid][i] = s;
    }
    __syncthreads();
    #pragma unroll
    for (int i = 0; i < TL; ++i) {
        float var = (red[0][i] + red[1][i] + red[2][i] + red[3][i]) * (1.f / 256.f);
        float r = 1.0f / sqrtf(var + EPSL);
        float v = (acc[i] - mean[i]) * r * gg + bb;
        out[((size_t)n * L_ + (l0 + i)) * C_ + c] = fmaxf(v, 0.f);
    }
}

// ---------------------------------------------------------------------------
// Kernel 2: conv1d + bias + LN + ReLU + linear(256->1) + ReLU + round -> dur
// ---------------------------------------------------------------------------
__global__ __launch_bounds__(256) void conv_ln_dur_kernel(
    const float* __restrict__ in, const float* __restrict__ w,
    const float* __restrict__ bias, const float* __restrict__ g,
    const float* __restrict__ beta, const float* __restrict__ lin_w,
    const float* __restrict__ lin_b, int* __restrict__ dur)
{
    __shared__ float xt[TL + 2][C_];
    __shared__ float red[4][TL];

    const int c    = threadIdx.x;
    const int lane = c & 63, wid = c >> 6;
    const int tile = blockIdx.x % (L_ / TL);
    const int n    = blockIdx.x / (L_ / TL);
    const int l0   = tile * TL;

    for (int r = 0; r < TL + 2; ++r) {
        int l = l0 - 1 + r;
        float v = 0.f;
        if (l >= 0 && l < L_) v = in[((size_t)n * L_ + l) * C_ + c];
        xt[r][c] = v;
    }
    __syncthreads();

    float acc[TL];
    #pragma unroll
    for (int i = 0; i < TL; ++i) acc[i] = 0.f;

    const float* wp = w + c;
    for (int cin = 0; cin < C_; ++cin) {
        float xv[TL + 2];
        #pragma unroll
        for (int r = 0; r < TL + 2; ++r) xv[r] = xt[r][cin];
        float w0 = wp[(size_t)cin * 256];
        float w1 = wp[(size_t)(256 + cin) * 256];
        float w2 = wp[(size_t)(512 + cin) * 256];
        #pragma unroll
        for (int i = 0; i < TL; ++i)
            acc[i] = fmaf(w0, xv[i], fmaf(w1, xv[i + 1], fmaf(w2, xv[i + 2], acc[i])));
    }

    const float bia = bias[c], gg = g[c], bb = beta[c];
    #pragma unroll
    for (int i = 0; i < TL; ++i) acc[i] += bia;

    float mean[TL];
    #pragma unroll
    for (int i = 0; i < TL; ++i) {
        float s = acc[i];
        #pragma unroll
        for (int off = 32; off > 0; off >>= 1) s += __shfl_down(s, off);
        if (lane == 0) red[wid][i] = s;
    }
    __syncthreads();
    #pragma unroll
    for (int i = 0; i < TL; ++i)
        mean[i] = (red[0][i] + red[1][i] + red[2][i] + red[3][i]) * (1.f / 256.f);
    __syncthreads();
    #pragma unroll
    for (int i = 0; i < TL; ++i) {
        float d = acc[i] - mean[i];
        float s = d * d;
        #pragma unroll
        for (int off = 32; off > 0; off >>= 1) s += __shfl_down(s, off);
        if (lane == 0) red[wid][i] = s;
    }
    __syncthreads();

    float hv[TL];
    #pragma unroll
    for (int i = 0; i < TL; ++i) {
        float var = (red[0][i] + red[1][i] + red[2][i] + red[3][i]) * (1.f / 256.f);
        float r = 1.0f / sqrtf(var + EPSL);
        float v = (acc[i] - mean[i]) * r * gg + bb;
        hv[i] = fmaxf(v, 0.f);
    }
    __syncthreads();

    // linear 256 -> 1
    const float lwv = lin_w[c];
    #pragma unroll
    for (int i = 0; i < TL; ++i) {
        float s = hv[i] * lwv;
        #pragma unroll
        for (int off = 32; off > 0; off >>= 1) s += __shfl_down(s, off);
        if (lane == 0) red[wid][i] = s;
    }
    __syncthreads();
    if (c < TL) {
        float dot = red[0][c] + red[1][c] + red[2][c] + red[3][c] + lin_b[0];
        float dpo = fmaxf(dot, 0.f);
        dur[n * L_ + l0 + c] = (int)(dpo + 0.5f);   // ALPHA = 1.0
    }
}

// ---------------------------------------------------------------------------
// Kernel 3: inclusive scan of dur over L per batch -> ends
// ---------------------------------------------------------------------------
__global__ __launch_bounds__(512) void scan_kernel(
    const int* __restrict__ dur, int* __restrict__ ends)
{
    __shared__ int s[2][L_];
    const int n = blockIdx.x, t = threadIdx.x;
    s[0][t] = dur[n * L_ + t];
    __syncthreads();
    int cur = 0;
    for (int off = 1; off < L_; off <<= 1) {
        int a = s[cur][t];
        if (t >= off) a += s[cur][t - off];
        s[cur ^ 1][t] = a;
        __syncthreads();
        cur ^= 1;
    }
    ends[n * L_ + t] = s[cur][t];
}

// ---------------------------------------------------------------------------
// Kernel 4: gather. wave-per-output-row; binary search over ends.
// ---------------------------------------------------------------------------
__global__ __launch_bounds__(256) void gather_kernel(
    const float* __restrict__ x, const int* __restrict__ ends,
    float* __restrict__ out)
{
    const int wid = threadIdx.x >> 6, lane = threadIdx.x & 63;
    const int row = blockIdx.x * 4 + wid;   // row = n*T + t
    const int n = row >> 12;                // T = 4096
    const int t = row & (T_ - 1);
    const int* e = ends + n * L_;
    const int total = e[L_ - 1];

    float4 v = make_float4(0.f, 0.f, 0.f, 0.f);
    if (t < total) {
        int pos = 0;                        // count of ends[l] <= t
        #pragma unroll
        for (int step = 256; step > 0; step >>= 1)
            if (pos + step <= L_ && e[pos + step - 1] <= t) pos += step;
        v = reinterpret_cast<const float4*>(x + ((size_t)n * L_ + pos) * C_)[lane];
    }
    reinterpret_cast<float4*>(out + (size_t)row * C_)[lane] = v;
}

// ---------------------------------------------------------------------------
// Kernel 5: WVF_pos tail = 1..T as float
// ---------------------------------------------------------------------------
__global__ void pos_kernel(float* __restrict__ o)
{
    int i = blockIdx.x * 256 + threadIdx.x;
    o[i] = (float)(i + 1);
}

// ---------------------------------------------------------------------------
extern "C" void kernel_launch(void* const* d_in, const int* in_sizes, int n_in,
                              void* d_out, int out_size, void* d_ws, size_t ws_size,
                              hipStream_t stream)
{
    const float* x   = (const float*)d_in[0];
    const float* w1  = (const float*)d_in[1];
    const float* b1  = (const float*)d_in[2];
    const float* g1  = (const float*)d_in[3];
    const float* be1 = (const float*)d_in[4];
    const float* w2  = (const float*)d_in[5];
    const float* b2  = (const float*)d_in[6];
    const float* g2  = (const float*)d_in[7];
    const float* be2 = (const float*)d_in[8];
    const float* lw  = (const float*)d_in[9];
    const float* lb  = (const float*)d_in[10];

    float* out = (float*)d_out;
    // h1 scratch lives in d_out's first 8 MiB (fully overwritten by gather later)
    float* h1  = out;
    int*   dur  = (int*)d_ws;              // 32 KB
    int*   ends = dur + N_ * L_;           // 32 KB

    const int conv_grid = N_ * (L_ / TL);  // 512 blocks

    conv_ln_relu_kernel<<<conv_grid, 256, 0, stream>>>(x, w1, b1, g1, be1, h1);
    conv_ln_dur_kernel <<<conv_grid, 256, 0, stream>>>(h1, w2, b2, g2, be2, lw, lb, dur);
    scan_kernel        <<<N_, L_, 0, stream>>>(dur, ends);
    gather_kernel      <<<N_ * T_ / 4, 256, 0, stream>>>(x, ends, out);
    pos_kernel         <<<T_ / 256, 256, 0, stream>>>(out + (size_t)N_ * T_ * C_);
}

// Round 2
// 85.911 us; speedup vs baseline: 1.8784x; 1.8784x over previous
//
#include <hip/hip_runtime.h>
#include <math.h>

#define N_   16
#define L_   512
#define C_   256
#define T_   4096
#define EPSL 1e-5f

typedef short short8 __attribute__((ext_vector_type(8)));
typedef float f32x4  __attribute__((ext_vector_type(4)));
typedef int   int4v  __attribute__((ext_vector_type(4)));

__device__ __forceinline__ ushort f2bf(float f) {
    union { float f; unsigned u; } v; v.f = f;
    unsigned r = (v.u + 0x7FFF + ((v.u >> 16) & 1)) >> 16;
    return (ushort)r;
}

// ---------------------------------------------------------------------------
// pack x (f32 -> bf16), 4 elems/thread
// ---------------------------------------------------------------------------
__global__ __launch_bounds__(256) void pack_x_kernel(
    const float* __restrict__ x, ushort* __restrict__ xb)
{
    int i = blockIdx.x * 256 + threadIdx.x;          // 524288 threads
    float4 v = reinterpret_cast<const float4*>(x)[i];
    ushort4 o;
    o.x = f2bf(v.x); o.y = f2bf(v.y); o.z = f2bf(v.z); o.w = f2bf(v.w);
    reinterpret_cast<ushort4*>(xb)[i] = o;
}

// ---------------------------------------------------------------------------
// pack conv weight transposed: wp[k][cout][cin] = bf16(w[k][cin][cout])
// ---------------------------------------------------------------------------
__global__ __launch_bounds__(256) void pack_w_kernel(
    const float* __restrict__ w, ushort* __restrict__ wp)
{
    int i = blockIdx.x * 256 + threadIdx.x;          // 196608 threads
    int cin = i & 255, cout = (i >> 8) & 255, k = i >> 16;
    wp[i] = f2bf(w[(k * 256 + cin) * 256 + cout]);
}

// ---------------------------------------------------------------------------
// MFMA conv1d(K=3) + bias + LayerNorm + ReLU  [+ linear->dur for MODE 1]
// block = 256 thr (4 waves), computes 16 rows x 256 cols. grid = 8192/16.
// wave w covers cols [w*64, w*64+64) via 4 col-frags of 16x16x32 MFMA.
// ---------------------------------------------------------------------------
template<int MODE>
__global__ __launch_bounds__(256) void conv_mfma_kernel(
    const ushort* __restrict__ in, const ushort* __restrict__ wp,
    const float* __restrict__ bias, const float* __restrict__ g,
    const float* __restrict__ beta, const float* __restrict__ lw,
    const float* __restrict__ lb, ushort* __restrict__ out,
    int* __restrict__ dur)
{
    __shared__ __align__(16) char xt[18 * 512];      // 18 rows x 256 bf16, swizzled
    __shared__ float redS[4][16], redQ[4][16];

    const int tid  = threadIdx.x;
    const int wv   = tid >> 6;
    const int lane = tid & 63;
    const int lg   = lane >> 4;                      // k-group 0..3
    const int lr   = lane & 15;                      // row/col-in-16
    const int row0 = blockIdx.x * 16;
    const int n    = row0 >> 9, l0 = row0 & 511;

    // stage rows l0-1 .. l0+16 (zero padded), 16B chunks, XOR slot swizzle
    for (int idx = tid; idx < 18 * 32; idx += 256) {
        int r = idx >> 5, c = idx & 31;
        int l = l0 - 1 + r;
        int4v v = {0, 0, 0, 0};
        if (l >= 0 && l < L_)
            v = *reinterpret_cast<const int4v*>(in + (((size_t)(n * L_ + l)) << 8) + (c << 3));
        *reinterpret_cast<int4v*>(xt + r * 512 + ((c ^ (r & 15)) << 4)) = v;
    }
    __syncthreads();

    f32x4 acc[4] = {};
    const int cout_base = wv * 64;

    for (int karm = 0; karm < 3; ++karm) {
        const ushort* wpk = wp + (((size_t)(karm * 256 + cout_base)) << 8);
        const int rA = lr + karm;                    // LDS row for this lane
        const int rbase = rA * 512;
        const int rx = rA & 15;
        #pragma unroll
        for (int s = 0; s < 8; ++s) {                // cin0 = s*32
            short8 a = *reinterpret_cast<const short8*>(
                xt + rbase + ((((s << 2) + lg) ^ rx) << 4));
            #pragma unroll
            for (int ft = 0; ft < 4; ++ft) {
                short8 b = *reinterpret_cast<const short8*>(
                    wpk + (((ft * 16 + lr) << 8) + (s << 5) + (lg << 3)));
                acc[ft] = __builtin_amdgcn_mfma_f32_16x16x32_bf16(a, b, acc[ft], 0, 0, 0);
            }
        }
    }

    // epilogue: bias, LN stats over 256 cols
    float bcol[4], gcol[4], becol[4], lwcol[4];
    #pragma unroll
    for (int ft = 0; ft < 4; ++ft) {
        int col = cout_base + ft * 16 + lr;
        bcol[ft] = bias[col]; gcol[ft] = g[col]; becol[ft] = beta[col];
        lwcol[ft] = (MODE == 1) ? lw[col] : 0.f;
    }

    f32x4 v[4];
    f32x4 s = {0, 0, 0, 0}, q = {0, 0, 0, 0};
    #pragma unroll
    for (int ft = 0; ft < 4; ++ft) {
        #pragma unroll
        for (int j = 0; j < 4; ++j) {
            float h = acc[ft][j] + bcol[ft];
            v[ft][j] = h;
            s[j] += h;
            q[j] += h * h;
        }
    }
    #pragma unroll
    for (int m = 1; m < 16; m <<= 1) {
        #pragma unroll
        for (int j = 0; j < 4; ++j) {
            s[j] += __shfl_xor(s[j], m, 64);
            q[j] += __shfl_xor(q[j], m, 64);
        }
    }
    if (lr == 0) {
        #pragma unroll
        for (int j = 0; j < 4; ++j) {
            redS[wv][lg * 4 + j] = s[j];
            redQ[wv][lg * 4 + j] = q[j];
        }
    }
    __syncthreads();

    float mean[4], rstd[4];
    #pragma unroll
    for (int j = 0; j < 4; ++j) {
        int rr = lg * 4 + j;
        float ss = redS[0][rr] + redS[1][rr] + redS[2][rr] + redS[3][rr];
        float qq = redQ[0][rr] + redQ[1][rr] + redQ[2][rr] + redQ[3][rr];
        float m_ = ss * (1.f / 256.f);
        float var = fmaxf(qq * (1.f / 256.f) - m_ * m_, 0.f);
        mean[j] = m_;
        rstd[j] = 1.0f / sqrtf(var + EPSL);
    }

    if (MODE == 0) {
        #pragma unroll
        for (int ft = 0; ft < 4; ++ft) {
            #pragma unroll
            for (int j = 0; j < 4; ++j) {
                float r = fmaxf((v[ft][j] - mean[j]) * rstd[j] * gcol[ft] + becol[ft], 0.f);
                out[(((size_t)(row0 + lg * 4 + j)) << 8) + cout_base + ft * 16 + lr] = f2bf(r);
            }
        }
    } else {
        f32x4 p = {0, 0, 0, 0};
        #pragma unroll
        for (int ft = 0; ft < 4; ++ft) {
            #pragma unroll
            for (int j = 0; j < 4; ++j) {
                float r = fmaxf((v[ft][j] - mean[j]) * rstd[j] * gcol[ft] + becol[ft], 0.f);
                p[j] += r * lwcol[ft];
            }
        }
        #pragma unroll
        for (int m = 1; m < 16; m <<= 1) {
            #pragma unroll
            for (int j = 0; j < 4; ++j) p[j] += __shfl_xor(p[j], m, 64);
        }
        __syncthreads();                              // redS reads above are done
        if (lr == 0) {
            #pragma unroll
            for (int j = 0; j < 4; ++j) redS[wv][lg * 4 + j] = p[j];
        }
        __syncthreads();
        if (tid < 16) {
            float dot = redS[0][tid] + redS[1][tid] + redS[2][tid] + redS[3][tid] + lb[0];
            dur[row0 + tid] = (int)(fmaxf(dot, 0.f) + 0.5f);
        }
    }
}

// ---------------------------------------------------------------------------
// inclusive scan of dur over L per batch -> ends
// ---------------------------------------------------------------------------
__global__ __launch_bounds__(512) void scan_kernel(
    const int* __restrict__ dur, int* __restrict__ ends)
{
    __shared__ int s[2][L_];
    const int n = blockIdx.x, t = threadIdx.x;
    s[0][t] = dur[n * L_ + t];
    __syncthreads();
    int cur = 0;
    for (int off = 1; off < L_; off <<= 1) {
        int a = s[cur][t];
        if (t >= off) a += s[cur][t - off];
        s[cur ^ 1][t] = a;
        __syncthreads();
        cur ^= 1;
    }
    ends[n * L_ + t] = s[cur][t];
}

// ---------------------------------------------------------------------------
// gather: wave-per-output-row; binary search over ends; float4 row copy
// ---------------------------------------------------------------------------
__global__ __launch_bounds__(256) void gather_kernel(
    const float* __restrict__ x, const int* __restrict__ ends,
    float* __restrict__ out)
{
    const int wid = threadIdx.x >> 6, lane = threadIdx.x & 63;
    const int row = blockIdx.x * 4 + wid;   // row = n*T + t
    const int n = row >> 12;
    const int t = row & (T_ - 1);
    const int* e = ends + n * L_;
    const int total = e[L_ - 1];

    float4 v = make_float4(0.f, 0.f, 0.f, 0.f);
    if (t < total) {
        int pos = 0;
        #pragma unroll
        for (int step = 256; step > 0; step >>= 1)
            if (pos + step <= L_ && e[pos + step - 1] <= t) pos += step;
        v = reinterpret_cast<const float4*>(x + ((size_t)n * L_ + pos) * C_)[lane];
    }
    reinterpret_cast<float4*>(out + (size_t)row * C_)[lane] = v;
}

// ---------------------------------------------------------------------------
__global__ void pos_kernel(float* __restrict__ o)
{
    int i = blockIdx.x * 256 + threadIdx.x;
    o[i] = (float)(i + 1);
}

// ---------------------------------------------------------------------------
extern "C" void kernel_launch(void* const* d_in, const int* in_sizes, int n_in,
                              void* d_out, int out_size, void* d_ws, size_t ws_size,
                              hipStream_t stream)
{
    const float* x   = (const float*)d_in[0];
    const float* w1  = (const float*)d_in[1];
    const float* b1  = (const float*)d_in[2];
    const float* g1  = (const float*)d_in[3];
    const float* be1 = (const float*)d_in[4];
    const float* w2  = (const float*)d_in[5];
    const float* b2  = (const float*)d_in[6];
    const float* g2  = (const float*)d_in[7];
    const float* be2 = (const float*)d_in[8];
    const float* lw  = (const float*)d_in[9];
    const float* lb  = (const float*)d_in[10];

    float* out = (float*)d_out;
    // scratch in d_out head: all dead before gather overwrites d_out
    ushort* xb  = (ushort*)d_out;                    // 2M bf16 = 4MB
    ushort* h1b = xb + 2 * 1024 * 1024;              // 2M bf16 = 4MB
    ushort* wp1 = h1b + 2 * 1024 * 1024;             // 196608 bf16
    ushort* wp2 = wp1 + 196608;                      // 196608 bf16
    int* dur  = (int*)d_ws;
    int* ends = dur + N_ * L_;

    pack_x_kernel<<<2048, 256, 0, stream>>>(x, xb);
    pack_w_kernel<<<768, 256, 0, stream>>>(w1, wp1);
    pack_w_kernel<<<768, 256, 0, stream>>>(w2, wp2);

    conv_mfma_kernel<0><<<512, 256, 0, stream>>>(xb, wp1, b1, g1, be1,
                                                 nullptr, nullptr, h1b, nullptr);
    conv_mfma_kernel<1><<<512, 256, 0, stream>>>(h1b, wp2, b2, g2, be2,
                                                 lw, lb, nullptr, dur);

    scan_kernel  <<<N_, L_, 0, stream>>>(dur, ends);
    gather_kernel<<<N_ * T_ / 4, 256, 0, stream>>>(x, ends, out);
    pos_kernel   <<<T_ / 256, 256, 0, stream>>>(out + (size_t)N_ * T_ * C_);
}

// Round 3
// 50.623 us; speedup vs baseline: 3.1878x; 1.6971x over previous
//
#include <hip/hip_runtime.h>
#include <math.h>

#define N_   16
#define L_   512
#define C_   256
#define T_   4096
#define EPSL 1e-5f

typedef short short8 __attribute__((ext_vector_type(8)));
typedef float f32x4  __attribute__((ext_vector_type(4)));

__device__ __forceinline__ ushort f2bf(float f) {
    union { float f; unsigned u; } v; v.f = f;
    unsigned r = (v.u + 0x7FFF + ((v.u >> 16) & 1)) >> 16;
    return (ushort)r;
}

// ---------------------------------------------------------------------------
// pack BOTH conv weights into MFMA-fragment order (bf16):
//   bpk[karm][cg(16)][s(8)][lane(64)][e(8)]
//   = w[karm][cin = s*32 + (lane>>4)*8 + e][cout = cg*16 + (lane&15)]
// One thread -> one 16B fragment chunk (8 bf16). 24576 threads per tensor.
// ---------------------------------------------------------------------------
__global__ __launch_bounds__(256) void pack_w_kernel(
    const float* __restrict__ w1, const float* __restrict__ w2,
    ushort* __restrict__ bpk1, ushort* __restrict__ bpk2)
{
    int gid = blockIdx.x * 256 + threadIdx.x;        // 49152 total
    const float* w  = (gid < 24576) ? w1 : w2;
    ushort* bpk     = (gid < 24576) ? bpk1 : bpk2;
    int g2 = gid & 24575;
    int lane = g2 & 63;
    int s    = (g2 >> 6) & 7;
    int cg   = (g2 >> 9) & 15;
    int karm = g2 >> 13;                             // 0..2
    int cin0 = s * 32 + (lane >> 4) * 8;
    int cout = cg * 16 + (lane & 15);
    const float* src = w + (size_t)(karm * 256 + cin0) * 256 + cout;
    short8 o;
    #pragma unroll
    for (int e = 0; e < 8; ++e) o[e] = (short)f2bf(src[(size_t)e * 256]);
    *reinterpret_cast<short8*>(bpk + (size_t)g2 * 8) = o;
}

// ---------------------------------------------------------------------------
// MFMA conv1d(K=3,'same') + bias + LayerNorm + ReLU [+ linear->dur, MODE 1]
// block = 512 thr (8 waves) computes 16 rows x 256 cols; wave = 16r x 32c.
// grid = 8192/16 = 512  ->  4 waves/SIMD.
// MODE 0: input f32 (x), output bf16.   MODE 1: input bf16, output dur int.
// ---------------------------------------------------------------------------
template<int MODE>
__global__ __launch_bounds__(512) void conv_mfma_kernel(
    const float* __restrict__ inf, const ushort* __restrict__ inb,
    const ushort* __restrict__ bpk,
    const float* __restrict__ bias, const float* __restrict__ g,
    const float* __restrict__ beta, const float* __restrict__ lw,
    const float* __restrict__ lb, ushort* __restrict__ out,
    int* __restrict__ dur)
{
    __shared__ __align__(16) char xt[18 * 512];      // 18 rows x 256 bf16, swizzled
    __shared__ float redS[8][16], redQ[8][16], redP[8][16];

    const int tid  = threadIdx.x;
    const int wv   = tid >> 6;                       // 0..7
    const int lane = tid & 63;
    const int lg   = lane >> 4;                      // 0..3
    const int lr   = lane & 15;
    const int row0 = blockIdx.x * 16;
    const int n    = row0 >> 9, l0 = row0 & 511;

    // stage rows l0-1 .. l0+16 (zero-padded), 16B bf16 slots, XOR swizzle
    for (int idx = tid; idx < 18 * 32; idx += 512) {
        int r = idx >> 5, slot = idx & 31;
        int l = l0 - 1 + r;
        short8 vb = {0, 0, 0, 0, 0, 0, 0, 0};
        if (l >= 0 && l < L_) {
            if (MODE == 0) {
                const float* src = inf + (((size_t)(n * L_ + l)) << 8) + (slot << 3);
                float4 f0 = *reinterpret_cast<const float4*>(src);
                float4 f1 = *reinterpret_cast<const float4*>(src + 4);
                vb[0] = (short)f2bf(f0.x); vb[1] = (short)f2bf(f0.y);
                vb[2] = (short)f2bf(f0.z); vb[3] = (short)f2bf(f0.w);
                vb[4] = (short)f2bf(f1.x); vb[5] = (short)f2bf(f1.y);
                vb[6] = (short)f2bf(f1.z); vb[7] = (short)f2bf(f1.w);
            } else {
                vb = *reinterpret_cast<const short8*>(
                    inb + (((size_t)(n * L_ + l)) << 8) + (slot << 3));
            }
        }
        *reinterpret_cast<short8*>(xt + r * 512 + ((slot ^ (r & 15)) << 4)) = vb;
    }
    __syncthreads();

    f32x4 acc0 = {}, acc1 = {};
    const int cg0 = wv * 2;                          // two 16-col groups per wave

    #pragma unroll
    for (int karm = 0; karm < 3; ++karm) {
        const int rA = lr + karm;
        const char* abase = xt + rA * 512;
        const int rx = rA & 15;
        const ushort* bb = bpk + (size_t)(karm * 16 + cg0) * 4096 + lane * 8;
        #pragma unroll
        for (int s = 0; s < 8; ++s) {
            short8 a = *reinterpret_cast<const short8*>(
                abase + ((((s << 2) + lg) ^ rx) << 4));
            short8 b0 = *reinterpret_cast<const short8*>(bb + s * 512);
            short8 b1 = *reinterpret_cast<const short8*>(bb + 4096 + s * 512);
            acc0 = __builtin_amdgcn_mfma_f32_16x16x32_bf16(a, b0, acc0, 0, 0, 0);
            acc1 = __builtin_amdgcn_mfma_f32_16x16x32_bf16(a, b1, acc1, 0, 0, 0);
        }
    }

    // epilogue: bias + LN stats over 256 cols (rows = lg*4+j of this tile)
    float bcol[2], gcol[2], becol[2], lwcol[2];
    #pragma unroll
    for (int ft = 0; ft < 2; ++ft) {
        int col = wv * 32 + ft * 16 + lr;
        bcol[ft] = bias[col]; gcol[ft] = g[col]; becol[ft] = beta[col];
        lwcol[ft] = (MODE == 1) ? lw[col] : 0.f;
    }

    float v[2][4];
    f32x4 s = {0, 0, 0, 0}, q = {0, 0, 0, 0};
    #pragma unroll
    for (int j = 0; j < 4; ++j) {
        float h0 = acc0[j] + bcol[0], h1 = acc1[j] + bcol[1];
        v[0][j] = h0; v[1][j] = h1;
        s[j] = h0 + h1;
        q[j] = h0 * h0 + h1 * h1;
    }
    #pragma unroll
    for (int m = 1; m < 16; m <<= 1) {
        #pragma unroll
        for (int j = 0; j < 4; ++j) {
            s[j] += __shfl_xor(s[j], m, 64);
            q[j] += __shfl_xor(q[j], m, 64);
        }
    }
    if (lr == 0) {
        #pragma unroll
        for (int j = 0; j < 4; ++j) {
            redS[wv][lg * 4 + j] = s[j];
            redQ[wv][lg * 4 + j] = q[j];
        }
    }
    __syncthreads();

    float mean[4], rstd[4];
    #pragma unroll
    for (int j = 0; j < 4; ++j) {
        int rr = lg * 4 + j;
        float ss = 0.f, qq = 0.f;
        #pragma unroll
        for (int u = 0; u < 8; ++u) { ss += redS[u][rr]; qq += redQ[u][rr]; }
        float m_ = ss * (1.f / 256.f);
        float var = fmaxf(qq * (1.f / 256.f) - m_ * m_, 0.f);
        mean[j] = m_;
        rstd[j] = 1.0f / sqrtf(var + EPSL);
    }

    if (MODE == 0) {
        #pragma unroll
        for (int ft = 0; ft < 2; ++ft) {
            #pragma unroll
            for (int j = 0; j < 4; ++j) {
                float r = fmaxf((v[ft][j] - mean[j]) * rstd[j] * gcol[ft] + becol[ft], 0.f);
                out[(((size_t)(row0 + lg * 4 + j)) << 8) + wv * 32 + ft * 16 + lr] = f2bf(r);
            }
        }
    } else {
        f32x4 p = {0, 0, 0, 0};
        #pragma unroll
        for (int ft = 0; ft < 2; ++ft) {
            #pragma unroll
            for (int j = 0; j < 4; ++j) {
                float r = fmaxf((v[ft][j] - mean[j]) * rstd[j] * gcol[ft] + becol[ft], 0.f);
                p[j] += r * lwcol[ft];
            }
        }
        #pragma unroll
        for (int m = 1; m < 16; m <<= 1) {
            #pragma unroll
            for (int j = 0; j < 4; ++j) p[j] += __shfl_xor(p[j], m, 64);
        }
        if (lr == 0) {
            #pragma unroll
            for (int j = 0; j < 4; ++j) redP[wv][lg * 4 + j] = p[j];
        }
        __syncthreads();
        if (tid < 16) {
            float dot = lb[0];
            #pragma unroll
            for (int u = 0; u < 8; ++u) dot += redP[u][tid];
            dur[row0 + tid] = (int)(fmaxf(dot, 0.f) + 0.5f);
        }
    }
}

// ---------------------------------------------------------------------------
// inclusive scan of dur over L per batch -> ends; also writes WVF_pos tail
// ---------------------------------------------------------------------------
__global__ __launch_bounds__(512) void scan_pos_kernel(
    const int* __restrict__ dur, int* __restrict__ ends, float* __restrict__ pos)
{
    __shared__ int s[2][L_];
    const int n = blockIdx.x, t = threadIdx.x;
    if (t < 256) pos[n * 256 + t] = (float)(n * 256 + t + 1);   // 16*256 = 4096
    s[0][t] = dur[n * L_ + t];
    __syncthreads();
    int cur = 0;
    for (int off = 1; off < L_; off <<= 1) {
        int a = s[cur][t];
        if (t >= off) a += s[cur][t - off];
        s[cur ^ 1][t] = a;
        __syncthreads();
        cur ^= 1;
    }
    ends[n * L_ + t] = s[cur][t];
}

// ---------------------------------------------------------------------------
// gather: wave-per-output-row; binary search over ends; float4 row copy
// ---------------------------------------------------------------------------
__global__ __launch_bounds__(256) void gather_kernel(
    const float* __restrict__ x, const int* __restrict__ ends,
    float* __restrict__ out)
{
    const int wid = threadIdx.x >> 6, lane = threadIdx.x & 63;
    const int row = blockIdx.x * 4 + wid;   // row = n*T + t
    const int n = row >> 12;
    const int t = row & (T_ - 1);
    const int* e = ends + n * L_;
    const int total = e[L_ - 1];

    float4 v = make_float4(0.f, 0.f, 0.f, 0.f);
    if (t < total) {
        int pos = 0;
        #pragma unroll
        for (int step = 256; step > 0; step >>= 1)
            if (pos + step <= L_ && e[pos + step - 1] <= t) pos += step;
        v = reinterpret_cast<const float4*>(x + ((size_t)n * L_ + pos) * C_)[lane];
    }
    reinterpret_cast<float4*>(out + (size_t)row * C_)[lane] = v;
}

// ---------------------------------------------------------------------------
extern "C" void kernel_launch(void* const* d_in, const int* in_sizes, int n_in,
                              void* d_out, int out_size, void* d_ws, size_t ws_size,
                              hipStream_t stream)
{
    const float* x   = (const float*)d_in[0];
    const float* w1  = (const float*)d_in[1];
    const float* b1  = (const float*)d_in[2];
    const float* g1  = (const float*)d_in[3];
    const float* be1 = (const float*)d_in[4];
    const float* w2  = (const float*)d_in[5];
    const float* b2  = (const float*)d_in[6];
    const float* g2  = (const float*)d_in[7];
    const float* be2 = (const float*)d_in[8];
    const float* lw  = (const float*)d_in[9];
    const float* lb  = (const float*)d_in[10];

    float* out = (float*)d_out;
    // scratch in d_out head: all dead before gather overwrites d_out
    ushort* h1b  = (ushort*)d_out;                   // 2M bf16 = 4MB
    ushort* bpk1 = h1b + 2 * 1024 * 1024;            // 196608 bf16
    ushort* bpk2 = bpk1 + 196608;                    // 196608 bf16
    int* dur  = (int*)d_ws;
    int* ends = dur + N_ * L_;

    pack_w_kernel<<<192, 256, 0, stream>>>(w1, w2, bpk1, bpk2);

    conv_mfma_kernel<0><<<512, 512, 0, stream>>>(x, nullptr, bpk1, b1, g1, be1,
                                                 nullptr, nullptr, h1b, nullptr);
    conv_mfma_kernel<1><<<512, 512, 0, stream>>>(nullptr, h1b, bpk2, b2, g2, be2,
                                                 lw, lb, nullptr, dur);

    scan_pos_kernel<<<N_, L_, 0, stream>>>(dur, ends, out + (size_t)N_ * T_ * C_);
    gather_kernel  <<<N_ * T_ / 4, 256, 0, stream>>>(x, ends, out);
}